// Round 1
// baseline (433.054 us; speedup 1.0000x reference)
//
#include <hip/hip_runtime.h>

// Problem constants (fixed by setup_inputs):
//   a_arc, s_arc : [64, 1024, 1024] f32
//   adds, pos    : [64, 1024] int32 in [0, 50)
//   n_pos = 50
constexpr int NPOS  = 50;
constexpr int NBINS = NPOS * NPOS;   // 2500
constexpr int SL    = 1024;
constexpr int BZ    = 64;
constexpr int ROWS_PER_BLOCK = 32;                       // rows of one batch per block
constexpr int BLOCKS_PER_B   = SL / ROWS_PER_BLOCK;      // 32
constexpr int NBLOCKS        = BZ * BLOCKS_PER_B;        // 2048
constexpr int NTHREADS       = 256;                      // 256 threads * float4 = 1024 = one row
constexpr float ALPHA = 0.3f;

// ---------------------------------------------------------------------------
// Kernel 1: per-block LDS histogram of a_arc keyed by adds[b,i]*50 + adds[b,j]
// ---------------------------------------------------------------------------
__global__ __launch_bounds__(NTHREADS) void hist_kernel(
    const float* __restrict__ a, const int* __restrict__ adds,
    float* __restrict__ g_hist) {
  __shared__ float shist[NBINS];   // 10 KB
  __shared__ int   adds_s[SL];     // 4 KB

  const int tid = threadIdx.x;
  const int b   = blockIdx.x / BLOCKS_PER_B;
  const int i0  = (blockIdx.x % BLOCKS_PER_B) * ROWS_PER_BLOCK;

  // Stage this batch's adds row (1024 ints) and zero the private histogram.
  ((int4*)adds_s)[tid] = ((const int4*)(adds + (size_t)b * SL))[tid];
  for (int k = tid; k < NBINS; k += NTHREADS) shist[k] = 0.0f;
  __syncthreads();

  // Each thread owns the same 4 columns j = 4*tid..4*tid+3 for every row.
  const int4 aj = ((const int4*)adds_s)[tid];
  const float4* __restrict__ arow =
      (const float4*)(a + ((size_t)b * SL + i0) * SL);

  for (int r = 0; r < ROWS_PER_BLOCK; ++r) {
    const int base = adds_s[i0 + r] * NPOS;        // broadcast LDS read
    const float4 av = arow[(size_t)r * (SL / 4) + tid];
    atomicAdd(&shist[base + aj.x], av.x);
    atomicAdd(&shist[base + aj.y], av.y);
    atomicAdd(&shist[base + aj.z], av.z);
    atomicAdd(&shist[base + aj.w], av.w);
  }
  __syncthreads();

  // Flush private histogram to the global one (d_ws), pre-zeroed on stream.
  for (int k = tid; k < NBINS; k += NTHREADS) {
    const float v = shist[k];
    if (v != 0.0f) atomicAdd(&g_hist[k], v);
  }
}

// ---------------------------------------------------------------------------
// Kernel 2: out = s_arc + ALPHA * sigmoid(hist)[pos[b,i]*50 + pos[b,j]]
// ---------------------------------------------------------------------------
__global__ __launch_bounds__(NTHREADS) void apply_kernel(
    const float* __restrict__ s, const int* __restrict__ pos,
    const float* __restrict__ g_hist, float* __restrict__ out) {
  __shared__ float sig[NBINS];    // 10 KB, sigmoid applied on load
  __shared__ int   pos_s[SL];     // 4 KB

  const int tid = threadIdx.x;
  const int b   = blockIdx.x / BLOCKS_PER_B;
  const int i0  = (blockIdx.x % BLOCKS_PER_B) * ROWS_PER_BLOCK;

  ((int4*)pos_s)[tid] = ((const int4*)(pos + (size_t)b * SL))[tid];
  for (int k = tid; k < NBINS; k += NTHREADS) {
    const float h = g_hist[k];
    sig[k] = 1.0f / (1.0f + __expf(-h));
  }
  __syncthreads();

  const int4 pj = ((const int4*)pos_s)[tid];
  const size_t rowoff = ((size_t)b * SL + i0) * SL;
  const float4* __restrict__ srow = (const float4*)(s + rowoff);
  float4* __restrict__ orow = (float4*)(out + rowoff);

  for (int r = 0; r < ROWS_PER_BLOCK; ++r) {
    const int base = pos_s[i0 + r] * NPOS;         // broadcast LDS read
    const float4 sv = srow[(size_t)r * (SL / 4) + tid];
    float4 ov;
    ov.x = sv.x + ALPHA * sig[base + pj.x];
    ov.y = sv.y + ALPHA * sig[base + pj.y];
    ov.z = sv.z + ALPHA * sig[base + pj.z];
    ov.w = sv.w + ALPHA * sig[base + pj.w];
    orow[(size_t)r * (SL / 4) + tid] = ov;
  }
}

extern "C" void kernel_launch(void* const* d_in, const int* in_sizes, int n_in,
                              void* d_out, int out_size, void* d_ws, size_t ws_size,
                              hipStream_t stream) {
  const float* a_arc = (const float*)d_in[0];
  const float* s_arc = (const float*)d_in[1];
  const int*   adds  = (const int*)d_in[2];
  const int*   pos   = (const int*)d_in[3];
  // d_in[4] is n_pos (=50), hard-coded as NPOS to keep bin arithmetic static.
  float* out    = (float*)d_out;
  float* g_hist = (float*)d_ws;   // NBINS floats = 10 KB of scratch

  // d_ws is NOT re-poisoned between timed replays; zero it ourselves each call.
  hipMemsetAsync(g_hist, 0, NBINS * sizeof(float), stream);

  hist_kernel <<<NBLOCKS, NTHREADS, 0, stream>>>(a_arc, adds, g_hist);
  apply_kernel<<<NBLOCKS, NTHREADS, 0, stream>>>(s_arc, pos, g_hist, out);
}